// Round 3
// baseline (1042.732 us; speedup 1.0000x reference)
//
#include <hip/hip_runtime.h>

#define NH 24
#define HD 128
#define DM 3072
#define DM3 9216
#define STXT 256
#define SIMG 2048
#define SALL 2304

typedef __attribute__((ext_vector_type(8))) short bfrag;
typedef __attribute__((ext_vector_type(4))) float ffrag;

__device__ __forceinline__ unsigned short f2bf(float f) {
  unsigned int x = __builtin_bit_cast(unsigned int, f);
  x += 0x7fffu + ((x >> 16) & 1u);
  return (unsigned short)(x >> 16);
}

// ---------------- cast fp32 -> bf16 (8 elems/thread) ----------------
__global__ __launch_bounds__(256) void cast_kernel(const float* __restrict__ in,
                                                   unsigned short* __restrict__ out) {
  int i = blockIdx.x * 256 + threadIdx.x;
  float4 a = ((const float4*)in)[2 * i];
  float4 b = ((const float4*)in)[2 * i + 1];
  uint4 o;
  o.x = (unsigned)f2bf(a.x) | ((unsigned)f2bf(a.y) << 16);
  o.y = (unsigned)f2bf(a.z) | ((unsigned)f2bf(a.w) << 16);
  o.z = (unsigned)f2bf(b.x) | ((unsigned)f2bf(b.y) << 16);
  o.w = (unsigned)f2bf(b.z) | ((unsigned)f2bf(b.w) << 16);
  ((uint4*)out)[i] = o;
}

// ---------------- W [K][N] fp32 -> Wt [N][K] bf16 (64x64 tiles) ----------------
__global__ __launch_bounds__(256) void transpose_cast_kernel(const float* __restrict__ W,
                                                             unsigned short* __restrict__ Wt,
                                                             int K, int N) {
  __shared__ __align__(16) unsigned short tile[64 * 72];  // [n][k], pad 8
  int k0 = blockIdx.y * 64, n0 = blockIdx.x * 64;
  int t = threadIdx.x;
  int rr = t >> 4, cc = (t & 15) * 4;
#pragma unroll
  for (int p = 0; p < 4; ++p) {
    int k = rr + p * 16;
    float4 v = *(const float4*)&W[(size_t)(k0 + k) * N + n0 + cc];
    tile[(cc + 0) * 72 + k] = f2bf(v.x);
    tile[(cc + 1) * 72 + k] = f2bf(v.y);
    tile[(cc + 2) * 72 + k] = f2bf(v.z);
    tile[(cc + 3) * 72 + k] = f2bf(v.w);
  }
  __syncthreads();
  int n = t >> 2, c = (t & 3) * 16;
  float4* dst = (float4*)&Wt[(size_t)(n0 + n) * K + k0 + c];
  dst[0] = *(float4*)&tile[n * 72 + c];
  dst[1] = *(float4*)&tile[n * 72 + c + 8];
}

// ---------------- GEMM: C = A[M][K] * Bt[N][K]^T + bias ----------------
// mode 0: QKV epilogue -> q,k fp32 scatter into qkvf[2][NH][SALL][HD], v bf16 -> Vt[NH][HD][SALL]
// mode 2: plain fp32 C[M][N] -> outf
__global__ __launch_bounds__(256) void gemm_bt(const unsigned short* __restrict__ A,
                                               const unsigned short* __restrict__ Bt,
                                               const float* __restrict__ bias,
                                               int M, int N, int K, int mode,
                                               float* __restrict__ outf,
                                               unsigned short* __restrict__ outb, int s_off) {
  __shared__ __align__(16) unsigned short As[128 * 40];
  __shared__ __align__(16) unsigned short Bs[128 * 40];
  const int tid = threadIdx.x;
  const int wave = tid >> 6, lane = tid & 63, quad = lane >> 4, l16 = lane & 15;
  const int wm = (wave >> 1) * 64, wn = (wave & 1) * 64;
  const size_t m0 = (size_t)blockIdx.y * 128, n0 = (size_t)blockIdx.x * 128;

  ffrag zf = {0.f, 0.f, 0.f, 0.f};
  ffrag acc[4][4];
#pragma unroll
  for (int i = 0; i < 4; ++i)
#pragma unroll
    for (int j = 0; j < 4; ++j) acc[i][j] = zf;

  const int sr = tid >> 2;
  const int sc = (tid & 3) * 8;
  const unsigned short* Ag = A + (m0 + sr) * K + sc;
  const unsigned short* Bg = Bt + (n0 + sr) * K + sc;

  for (int k0 = 0; k0 < K; k0 += 32) {
    __syncthreads();
    *(bfrag*)&As[sr * 40 + sc] = *(const bfrag*)&Ag[k0];
    *(bfrag*)&As[(sr + 64) * 40 + sc] = *(const bfrag*)&Ag[(size_t)64 * K + k0];
    *(bfrag*)&Bs[sr * 40 + sc] = *(const bfrag*)&Bg[k0];
    *(bfrag*)&Bs[(sr + 64) * 40 + sc] = *(const bfrag*)&Bg[(size_t)64 * K + k0];
    __syncthreads();
    bfrag af[4], bfv[4];
#pragma unroll
    for (int mt = 0; mt < 4; ++mt)
      af[mt] = *(const bfrag*)&As[(wm + mt * 16 + l16) * 40 + quad * 8];
#pragma unroll
    for (int nt = 0; nt < 4; ++nt)
      bfv[nt] = *(const bfrag*)&Bs[(wn + nt * 16 + l16) * 40 + quad * 8];
#pragma unroll
    for (int mt = 0; mt < 4; ++mt)
#pragma unroll
      for (int nt = 0; nt < 4; ++nt)
        acc[mt][nt] = __builtin_amdgcn_mfma_f32_16x16x32_bf16(af[mt], bfv[nt], acc[mt][nt], 0, 0, 0);
  }

  float bv[4];
#pragma unroll
  for (int nt = 0; nt < 4; ++nt) bv[nt] = bias[n0 + wn + nt * 16 + l16];

#pragma unroll
  for (int mt = 0; mt < 4; ++mt) {
#pragma unroll
    for (int nt = 0; nt < 4; ++nt) {
      int gn = (int)n0 + wn + nt * 16 + l16;
#pragma unroll
      for (int r = 0; r < 4; ++r) {
        float v = acc[mt][nt][r] + bv[nt];
        int gm = (int)m0 + wm + mt * 16 + quad * 4 + r;
        if (mode == 2) {
          outf[(size_t)gm * N + gn] = v;
        } else {
          int which = gn / DM;
          int rr2 = gn - which * DM;
          int head = rr2 >> 7, d = rr2 & 127;
          int s = s_off + gm;
          if (which < 2)
            outf[(((size_t)which * NH + head) * SALL + s) * HD + d] = v;
          else
            outb[((size_t)head * HD + d) * SALL + s] = f2bf(v);
        }
      }
    }
  }
}

// ---------------- fused RMSNorm + RoPE on q,k ----------------
// qkvf: [2][NH][SALL][HD] fp32 -> Qb/Kb bf16 [NH][SALL][HD]
__global__ __launch_bounds__(256) void norm_rope_kernel(
    const float* __restrict__ qkvf, const float* __restrict__ gq, const float* __restrict__ gk,
    const float* __restrict__ gaq, const float* __restrict__ gak,
    const float* __restrict__ img_cos, const float* __restrict__ img_sin,
    const float* __restrict__ txt_cos, const float* __restrict__ txt_sin,
    unsigned short* __restrict__ Qb, unsigned short* __restrict__ Kb) {
  int wave = threadIdx.x >> 6, lane = threadIdx.x & 63;
  int row = blockIdx.x * 4 + wave;  // < 2*NH*SALL
  int which = row / (NH * SALL);
  int rem = row - which * (NH * SALL);
  int s = rem % SALL;
  float2 v = *(const float2*)&qkvf[(size_t)row * HD + lane * 2];
  float ss = v.x * v.x + v.y * v.y;
#pragma unroll
  for (int m = 1; m < 64; m <<= 1) ss += __shfl_xor(ss, m);
  float rinv = rsqrtf(ss * (1.0f / 128.0f) + 1e-6f);
  bool is_txt = s < STXT;
  int pos = is_txt ? s : s - STXT;
  const float* g = (which == 0) ? (is_txt ? gaq : gq) : (is_txt ? gak : gk);
  const float* ct = is_txt ? txt_cos : img_cos;
  const float* st = is_txt ? txt_sin : img_sin;
  float c = ct[pos * 64 + lane], sn = st[pos * 64 + lane];
  float x0 = v.x * rinv * g[lane * 2];
  float x1 = v.y * rinv * g[lane * 2 + 1];
  float o0 = x0 * c - x1 * sn;
  float o1 = x0 * sn + x1 * c;
  unsigned short* out = (which == 0 ? Qb : Kb) + (size_t)rem * HD + lane * 2;
  *(unsigned int*)out = (unsigned)f2bf(o0) | ((unsigned)f2bf(o1) << 16);
}

// ---------------- flash attention ----------------
// Q,K: [NH][SALL][HD] bf16; Vt: [NH][HD][SALL] bf16; attn: [SALL][NH*HD] bf16
// grid (SALL/64, NH), 256 threads; each wave owns 16 q-rows; key tiles of 64.
__global__ __launch_bounds__(256) void flash_kernel(const unsigned short* __restrict__ Q,
                                                    const unsigned short* __restrict__ Kg,
                                                    const unsigned short* __restrict__ Vt,
                                                    unsigned short* __restrict__ attn) {
  __shared__ __align__(16) unsigned short Kl[64 * 136];   // [key][d] pad 8
  __shared__ __align__(16) unsigned short Vl[128 * 72];   // [d][key] pad 8
  __shared__ __align__(16) unsigned short Pl[4 * 16 * 72];// per-wave [q][key] pad 8
  const int h = blockIdx.y;
  const int qb = blockIdx.x * 64;
  const int tid = threadIdx.x;
  const int wave = tid >> 6, lane = tid & 63, quad = lane >> 4, l16 = lane & 15;

  // Q fragments (A operand), rows qb + wave*16 + l16
  const unsigned short* qrow = Q + ((size_t)h * SALL + qb + wave * 16 + l16) * HD;
  bfrag aq[4];
#pragma unroll
  for (int kk = 0; kk < 4; ++kk) aq[kk] = *(const bfrag*)&qrow[kk * 32 + quad * 8];

  ffrag zf = {0.f, 0.f, 0.f, 0.f};
  ffrag o[8];
#pragma unroll
  for (int i = 0; i < 8; ++i) o[i] = zf;
  float m_r[4] = {-__builtin_inff(), -__builtin_inff(), -__builtin_inff(), -__builtin_inff()};
  float l_r[4] = {0.f, 0.f, 0.f, 0.f};
  const float sc = 0.08838834764831845f * 1.4426950408889634f;  // 1/sqrt(128) * log2(e)

  for (int kb = 0; kb < SALL; kb += 64) {
    __syncthreads();
    {  // stage K tile [64][128]
      int r_ = tid >> 4, c_ = (tid & 15) * 8;
#pragma unroll
      for (int p = 0; p < 4; ++p)
        *(bfrag*)&Kl[(r_ + p * 16) * 136 + c_] =
            *(const bfrag*)&Kg[((size_t)h * SALL + kb + r_ + p * 16) * HD + c_];
      // stage V^T tile [128][64]
      int dr = tid >> 3, dc = (tid & 7) * 8;
#pragma unroll
      for (int p = 0; p < 4; ++p)
        *(bfrag*)&Vl[(dr + p * 32) * 72 + dc] =
            *(const bfrag*)&Vt[((size_t)h * HD + dr + p * 32) * SALL + kb + dc];
    }
    __syncthreads();

    // QK^T: 4 n-tiles of 16 keys
    ffrag s_[4];
#pragma unroll
    for (int nt = 0; nt < 4; ++nt) s_[nt] = zf;
#pragma unroll
    for (int kk = 0; kk < 4; ++kk) {
#pragma unroll
      for (int nt = 0; nt < 4; ++nt) {
        bfrag kf = *(const bfrag*)&Kl[(nt * 16 + l16) * 136 + kk * 32 + quad * 8];
        s_[nt] = __builtin_amdgcn_mfma_f32_16x16x32_bf16(aq[kk], kf, s_[nt], 0, 0, 0);
      }
    }
    // scale into exp2 domain
#pragma unroll
    for (int nt = 0; nt < 4; ++nt)
#pragma unroll
      for (int r = 0; r < 4; ++r) s_[nt][r] *= sc;

    float alpha[4], rowsum[4];
#pragma unroll
    for (int r = 0; r < 4; ++r) {
      float mx = fmaxf(fmaxf(s_[0][r], s_[1][r]), fmaxf(s_[2][r], s_[3][r]));
#pragma unroll
      for (int msk = 1; msk < 16; msk <<= 1) mx = fmaxf(mx, __shfl_xor(mx, msk));
      float mnew = fmaxf(m_r[r], mx);
      alpha[r] = exp2f(m_r[r] - mnew);
      m_r[r] = mnew;
      float rs = 0.f;
#pragma unroll
      for (int nt = 0; nt < 4; ++nt) {
        float p = exp2f(s_[nt][r] - mnew);
        s_[nt][r] = p;
        rs += p;
      }
#pragma unroll
      for (int msk = 1; msk < 16; msk <<= 1) rs += __shfl_xor(rs, msk);
      rowsum[r] = rs;
      l_r[r] = l_r[r] * alpha[r] + rowsum[r];
    }
    // rescale O
#pragma unroll
    for (int dt = 0; dt < 8; ++dt)
#pragma unroll
      for (int r = 0; r < 4; ++r) o[dt][r] *= alpha[r];
    // write P (C layout -> LDS) as bf16
#pragma unroll
    for (int r = 0; r < 4; ++r)
#pragma unroll
      for (int nt = 0; nt < 4; ++nt)
        Pl[wave * 16 * 72 + (quad * 4 + r) * 72 + nt * 16 + l16] = f2bf(s_[nt][r]);
    __syncthreads();

    // PV: P is A operand [q][key], V^T rows are B operand
    bfrag pf0 = *(const bfrag*)&Pl[wave * 16 * 72 + l16 * 72 + quad * 8];
    bfrag pf1 = *(const bfrag*)&Pl[wave * 16 * 72 + l16 * 72 + 32 + quad * 8];
#pragma unroll
    for (int dt = 0; dt < 8; ++dt) {
      bfrag vf0 = *(const bfrag*)&Vl[(dt * 16 + l16) * 72 + quad * 8];
      bfrag vf1 = *(const bfrag*)&Vl[(dt * 16 + l16) * 72 + 32 + quad * 8];
      o[dt] = __builtin_amdgcn_mfma_f32_16x16x32_bf16(pf0, vf0, o[dt], 0, 0, 0);
      o[dt] = __builtin_amdgcn_mfma_f32_16x16x32_bf16(pf1, vf1, o[dt], 0, 0, 0);
    }
  }

  // epilogue: normalize and write attn[s][h*HD + d]
  float linv[4];
#pragma unroll
  for (int r = 0; r < 4; ++r) linv[r] = 1.0f / l_r[r];
#pragma unroll
  for (int dt = 0; dt < 8; ++dt) {
#pragma unroll
    for (int r = 0; r < 4; ++r) {
      int s = qb + wave * 16 + quad * 4 + r;
      attn[(size_t)s * DM + h * HD + dt * 16 + l16] = f2bf(o[dt][r] * linv[r]);
    }
  }
}

// ---------------- launch ----------------
extern "C" void kernel_launch(void* const* d_in, const int* in_sizes, int n_in,
                              void* d_out, int out_size, void* d_ws, size_t ws_size,
                              hipStream_t stream) {
  const float* image = (const float*)d_in[0];
  const float* text = (const float*)d_in[1];
  const float* img_cos = (const float*)d_in[2];
  const float* img_sin = (const float*)d_in[3];
  const float* txt_cos = (const float*)d_in[4];
  const float* txt_sin = (const float*)d_in[5];
  const float* Wqkv = (const float*)d_in[6];
  const float* bqkv = (const float*)d_in[7];
  const float* Wadd = (const float*)d_in[8];
  const float* badd = (const float*)d_in[9];
  const float* gq = (const float*)d_in[10];
  const float* gk = (const float*)d_in[11];
  const float* gaq = (const float*)d_in[12];
  const float* gak = (const float*)d_in[13];
  const float* Wout = (const float*)d_in[14];
  const float* bout = (const float*)d_in[15];
  const float* Waddout = (const float*)d_in[16];
  const float* baddout = (const float*)d_in[17];

  char* ws = (char*)d_ws;
  size_t off = 0;
  // img_bf/txt_bf are dead after the QKV GEMMs; attn (same total size) aliases them.
  unsigned short* img_bf = (unsigned short*)(ws + off); off += (size_t)SIMG * DM * 2;      // 12.6 MB
  unsigned short* txt_bf = (unsigned short*)(ws + off); off += (size_t)STXT * DM * 2;      // 1.6 MB
  unsigned short* attn = img_bf;  // alias: [SALL][DM] bf16 = 14.2 MB, written by flash only
  unsigned short* Wqkv_t = (unsigned short*)(ws + off); off += (size_t)DM3 * DM * 2;       // 56.6 MB
  unsigned short* Wadd_t = (unsigned short*)(ws + off); off += (size_t)DM3 * DM * 2;       // 56.6 MB
  unsigned short* Wout_t = (unsigned short*)(ws + off); off += (size_t)DM * DM * 2;        // 18.9 MB
  unsigned short* Waddout_t = (unsigned short*)(ws + off); off += (size_t)DM * DM * 2;     // 18.9 MB
  float* qkvf = (float*)(ws + off); off += (size_t)2 * NH * SALL * HD * 4;                 // 56.6 MB
  unsigned short* Qb = (unsigned short*)(ws + off); off += (size_t)NH * SALL * HD * 2;     // 14.2 MB
  unsigned short* Kb = (unsigned short*)(ws + off); off += (size_t)NH * SALL * HD * 2;     // 14.2 MB
  unsigned short* Vtb = (unsigned short*)(ws + off); off += (size_t)NH * HD * SALL * 2;    // 14.2 MB
  if (off > ws_size) return;  // workspace too small: bail (will fail validation loudly)

  cast_kernel<<<SIMG * DM / 2048, 256, 0, stream>>>(image, img_bf);
  cast_kernel<<<STXT * DM / 2048, 256, 0, stream>>>(text, txt_bf);
  transpose_cast_kernel<<<dim3(DM3 / 64, DM / 64), 256, 0, stream>>>(Wqkv, Wqkv_t, DM, DM3);
  transpose_cast_kernel<<<dim3(DM3 / 64, DM / 64), 256, 0, stream>>>(Wadd, Wadd_t, DM, DM3);
  transpose_cast_kernel<<<dim3(DM / 64, DM / 64), 256, 0, stream>>>(Wout, Wout_t, DM, DM);
  transpose_cast_kernel<<<dim3(DM / 64, DM / 64), 256, 0, stream>>>(Waddout, Waddout_t, DM, DM);

  // QKV projections (epilogue scatters q,k fp32 + v bf16 transposed)
  gemm_bt<<<dim3(DM3 / 128, SIMG / 128), 256, 0, stream>>>(img_bf, Wqkv_t, bqkv, SIMG, DM3, DM,
                                                           0, qkvf, Vtb, STXT);
  gemm_bt<<<dim3(DM3 / 128, STXT / 128), 256, 0, stream>>>(txt_bf, Wadd_t, badd, STXT, DM3, DM,
                                                           0, qkvf, Vtb, 0);

  norm_rope_kernel<<<2 * NH * SALL / 4, 256, 0, stream>>>(qkvf, gq, gk, gaq, gak, img_cos,
                                                          img_sin, txt_cos, txt_sin, Qb, Kb);

  flash_kernel<<<dim3(SALL / 64, NH), 256, 0, stream>>>(Qb, Kb, Vtb, attn);

  // output projections straight into d_out (img_out first, then txt_out)
  gemm_bt<<<dim3(DM / 128, SIMG / 128), 256, 0, stream>>>(attn + (size_t)STXT * DM, Wout_t, bout,
                                                          SIMG, DM, DM, 2, (float*)d_out, nullptr, 0);
  gemm_bt<<<dim3(DM / 128, STXT / 128), 256, 0, stream>>>(attn, Waddout_t, baddout, STXT, DM, DM,
                                                          2, (float*)d_out + (size_t)SIMG * DM,
                                                          nullptr, 0);
}